// Round 8
// baseline (198.583 us; speedup 1.0000x reference)
//
#include <hip/hip_runtime.h>
#include <math.h>

#define NFILT 64
#define FRAME_STEP 160
#define WMAX 24            // max nonzero span of one mel filter (verified R1-R7)
#define WSTRIDE 25         // gcd(25,32)=1 -> conflict-free lane-indexed LDS reads
#define WAVES 4
#define NBLOCKS 1563       // 6252 waves; 12500 pair-groups -> 2 groups per wave
#define PWBINS 280         // 257 bins + pad so the mel window can overrun

// ---- load one 400-sample frame (8/lane, lanes 0..49) + pre-emphasis ----
__device__ __forceinline__ void load_pre(const float* __restrict__ x, long base,
                                         int l, bool valid, float (&v)[8]) {
    float a0=0,a1=0,a2=0,a3=0,a4=0,a5=0,a6=0,a7=0;
    if (valid && l < 50) {
        const float4* p4 = reinterpret_cast<const float4*>(x + base + 8 * l);
        float4 A = p4[0], B = p4[1];
        a0=A.x; a1=A.y; a2=A.z; a3=A.w; a4=B.x; a5=B.y; a6=B.z; a7=B.w;
    }
    float edge = 0.0f;
    if (valid && base > 0) edge = x[base - 1];   // pre[0] of audio = x[0] - 0.97*0
    float prev = __shfl_up(a7, 1, 64);
    if (l == 0) prev = edge;
    const bool act = valid && (l < 50);
    v[0] = act ? fmaf(-0.97f, prev, a0) : 0.0f;
    v[1] = act ? fmaf(-0.97f, a0, a1) : 0.0f;
    v[2] = act ? fmaf(-0.97f, a1, a2) : 0.0f;
    v[3] = act ? fmaf(-0.97f, a2, a3) : 0.0f;
    v[4] = act ? fmaf(-0.97f, a3, a4) : 0.0f;
    v[5] = act ? fmaf(-0.97f, a4, a5) : 0.0f;
    v[6] = act ? fmaf(-0.97f, a5, a6) : 0.0f;
    v[7] = act ? fmaf(-0.97f, a6, a7) : 0.0f;
}

// ---- one cross-lane DIF stage on TWO pairs, shuffles batched 32-deep ----
__device__ __forceinline__ void fftstage_x2(float (&vrA)[8], float (&viA)[8],
                                            float (&vrB)[8], float (&viB)[8],
                                            int d, float c, float s, float g) {
    float prA[8], piA[8], prB[8], piB[8];
#pragma unroll
    for (int r = 0; r < 8; r++) {
        prA[r] = __shfl_xor(vrA[r], d, 64);
        piA[r] = __shfl_xor(viA[r], d, 64);
    }
#pragma unroll
    for (int r = 0; r < 8; r++) {
        prB[r] = __shfl_xor(vrB[r], d, 64);
        piB[r] = __shfl_xor(viB[r], d, 64);
    }
#pragma unroll
    for (int r = 0; r < 8; r++) {
        float tr = fmaf(g, vrA[r], prA[r]), ti = fmaf(g, viA[r], piA[r]);
        vrA[r] = tr * c - ti * s;
        viA[r] = tr * s + ti * c;
    }
#pragma unroll
    for (int r = 0; r < 8; r++) {
        float tr = fmaf(g, vrB[r], prB[r]), ti = fmaf(g, viB[r], piB[r]);
        vrB[r] = tr * c - ti * s;
        viB[r] = tr * s + ti * c;
    }
}

// ---- W512^{n2*k1} twiddle + in-register 8-pt DIF (R3-verified math) ----
__device__ __forceinline__ void twiddle_radix8(float (&vr)[8], float (&vi)[8],
                                               const float (&br)[8], const float (&bi)[8]) {
#pragma unroll
    for (int r = 1; r < 8; r++) {
        float tr = vr[r], ti = vi[r];
        vr[r] = tr * br[r] - ti * bi[r];
        vi[r] = tr * bi[r] + ti * br[r];
    }
    const float RH = 0.70710678118654752f;
    {
        float t0r=vr[0]+vr[4], t0i=vi[0]+vi[4];
        float d0r=vr[0]-vr[4], d0i=vi[0]-vi[4];
        float t1r=vr[1]+vr[5], t1i=vi[1]+vi[5];
        float d1r=vr[1]-vr[5], d1i=vi[1]-vi[5];
        float t2r=vr[2]+vr[6], t2i=vi[2]+vi[6];
        float d2r=vr[2]-vr[6], d2i=vi[2]-vi[6];
        float t3r=vr[3]+vr[7], t3i=vi[3]+vi[7];
        float d3r=vr[3]-vr[7], d3i=vi[3]-vi[7];
        vr[0]=t0r; vi[0]=t0i; vr[1]=t1r; vi[1]=t1i;
        vr[2]=t2r; vi[2]=t2i; vr[3]=t3r; vi[3]=t3i;
        vr[4]=d0r;                 vi[4]=d0i;
        vr[5]=(d1r+d1i)*RH;        vi[5]=(d1i-d1r)*RH;
        vr[6]=d2i;                 vi[6]=-d2r;
        vr[7]=(d3i-d3r)*RH;        vi[7]=-(d3r+d3i)*RH;
    }
    {
        float t0r=vr[0]+vr[2], t0i=vi[0]+vi[2];
        float d0r=vr[0]-vr[2], d0i=vi[0]-vi[2];
        float t1r=vr[1]+vr[3], t1i=vi[1]+vi[3];
        float d1r=vr[1]-vr[3], d1i=vi[1]-vi[3];
        vr[0]=t0r; vi[0]=t0i; vr[1]=t1r; vi[1]=t1i;
        vr[2]=d0r; vi[2]=d0i; vr[3]=d1i; vi[3]=-d1r;
        float t4r=vr[4]+vr[6], t4i=vi[4]+vi[6];
        float d4r=vr[4]-vr[6], d4i=vi[4]-vi[6];
        float t5r=vr[5]+vr[7], t5i=vi[5]+vi[7];
        float d5r=vr[5]-vr[7], d5i=vi[5]-vi[7];
        vr[4]=t4r; vi[4]=t4i; vr[5]=t5r; vi[5]=t5i;
        vr[6]=d4r; vi[6]=d4i; vr[7]=d5i; vi[7]=-d5r;
    }
    {
        float t0r=vr[0]+vr[1], t0i=vi[0]+vi[1];
        float d0r=vr[0]-vr[1], d0i=vi[0]-vi[1];
        vr[0]=t0r; vi[0]=t0i; vr[1]=d0r; vi[1]=d0i;
        float t2r=vr[2]+vr[3], t2i=vi[2]+vi[3];
        float d2r=vr[2]-vr[3], d2i=vi[2]-vi[3];
        vr[2]=t2r; vi[2]=t2i; vr[3]=d2r; vi[3]=d2i;
        float t4r=vr[4]+vr[5], t4i=vi[4]+vi[5];
        float d4r=vr[4]-vr[5], d4i=vi[4]-vi[5];
        vr[4]=t4r; vi[4]=t4i; vr[5]=d4r; vi[5]=d4i;
        float t6r=vr[6]+vr[7], t6i=vi[6]+vi[7];
        float d6r=vr[6]-vr[7], d6i=vi[6]-vi[7];
        vr[6]=t6r; vi[6]=t6i; vr[7]=d6r; vi[7]=d6i;
    }
}

// ---- conj-symmetry untangle (z = a + i b) + power -> LDS (R3/R4-verified) ----
__device__ __forceinline__ void untangle_power(const float (&vr)[8], const float (&vi)[8],
                                               int l, int rl, int Lp,
                                               float* __restrict__ pwrow) {
    float c0r = __shfl(vr[7], Lp, 64), c0i = __shfl(vi[7], Lp, 64);  // p=0
    float c1r = __shfl(vr[3], Lp, 64), c1i = __shfl(vi[3], Lp, 64);  // p=4
    float c2r = __shfl(vr[5], Lp, 64), c2i = __shfl(vi[5], Lp, 64);  // p=2
    float c3r = __shfl(vr[1], Lp, 64), c3i = __shfl(vi[1], Lp, 64);  // p=6
    if (l == 0) {
        c0r = vr[0]; c0i = vi[0];
        c1r = vr[7]; c1i = vi[7];
        c2r = vr[3]; c2i = vi[3];
        c3r = vr[5]; c3i = vi[5];
    }
    const float S4 = (1.0f / 512.0f) * 0.25f;
    {
        float zr = vr[0], zi = vi[0];
        float e1 = zr + c0r, e2 = zi - c0i, o1 = zi + c0i, o2 = c0r - zr;
        *reinterpret_cast<float2*>(&pwrow[2 * rl]) =
            make_float2((e1*e1 + e2*e2) * S4, (o1*o1 + o2*o2) * S4);
    }
    {
        float zr = vr[4], zi = vi[4];
        float e1 = zr + c1r, e2 = zi - c1i, o1 = zi + c1i, o2 = c1r - zr;
        *reinterpret_cast<float2*>(&pwrow[2 * (rl + 64)]) =
            make_float2((e1*e1 + e2*e2) * S4, (o1*o1 + o2*o2) * S4);
    }
    {
        float zr = vr[2], zi = vi[2];
        float e1 = zr + c2r, e2 = zi - c2i, o1 = zi + c2i, o2 = c2r - zr;
        *reinterpret_cast<float2*>(&pwrow[2 * (rl + 128)]) =
            make_float2((e1*e1 + e2*e2) * S4, (o1*o1 + o2*o2) * S4);
    }
    {
        float zr = vr[6], zi = vi[6];
        float e1 = zr + c3r, e2 = zi - c3i, o1 = zi + c3i, o2 = c3r - zr;
        *reinterpret_cast<float2*>(&pwrow[2 * (rl + 192)]) =
            make_float2((e1*e1 + e2*e2) * S4, (o1*o1 + o2*o2) * S4);
    }
    if (l == 0) {   // bin 256 pairs with itself: Xa=Re(Z[256]), Xb=Im(Z[256])
        pwrow[512] = vr[1] * vr[1] * (1.0f / 512.0f);
        pwrow[513] = vi[1] * vi[1] * (1.0f / 512.0f);
    }
}

// 4 independent full-wave sum chains, interleaved in the issue stream
__device__ __forceinline__ void sum64x4(float &a, float &b, float &c, float &d) {
#pragma unroll
    for (int mk = 1; mk < 64; mk <<= 1) {
        a += __shfl_xor(a, mk, 64);
        b += __shfl_xor(b, mk, 64);
        c += __shfl_xor(c, mk, 64);
        d += __shfl_xor(d, mk, 64);
    }
}

__global__ __launch_bounds__(256) void fbank_kernel(const float* __restrict__ x,
                                                    const float* __restrict__ filters,
                                                    float* __restrict__ out,
                                                    int num_frames) {
    __shared__ float wc_lds[NFILT * WSTRIDE];
    __shared__ int   lo_lds[NFILT];
    __shared__ float pw[WAVES][2][PWBINS * 2];   // [wave][pairA/pairB][(pa,pb) per bin]

    const int t = threadIdx.x;
    const int l = t & 63;
    const int w = t >> 6;
    float* pw0 = pw[w][0];
    float* pw1 = pw[w][1];

    // zero pad bins [257, PWBINS) once (never rewritten)
    if (l < 2 * (PWBINS - 257)) {
        pw0[2 * 257 + l] = 0.0f;
        pw1[2 * 257 + l] = 0.0f;
    }

    // ---- wave 0: batched filter-window scan (R4/R6-verified) ----
    if (w == 0) {
        int lo = 257;
#pragma unroll 4
        for (int k0 = 0; k0 < 264; k0 += 8) {
            float fv[8];
#pragma unroll
            for (int i = 0; i < 8; i++) {
                int k = k0 + i;
                fv[i] = (k < 257) ? filters[k * NFILT + l] : 0.0f;
            }
#pragma unroll
            for (int i = 0; i < 8; i++) {
                if (fv[i] != 0.0f && lo == 257) lo = k0 + i;
            }
        }
        if (lo > 256) lo = 256;
        lo_lds[l] = lo;
        for (int i = 0; i < WMAX; i++) {
            int k = lo + i;
            wc_lds[l * WSTRIDE + i] = (k <= 256) ? filters[k * NFILT + l] : 0.0f;
        }
    }

    // ---- loop-invariant twiddles (registers) ----
    const int rl = (int)(__brev((unsigned)l) >> 26);    // rev6(lane) = k1
    float cA[6], sA[6], sg[6];
#pragma unroll
    for (int j = 0; j < 6; j++) {
        const int d = 32 >> j;
        const int hi = l & d;
        float th = -2.0f * (float)M_PI * (float)(l & (d - 1)) / (float)(2 * d);
        cA[j] = hi ? cosf(th) : 1.0f;
        sA[j] = hi ? sinf(th) : 0.0f;
        sg[j] = hi ? -1.0f : 1.0f;
    }
    float br[8], bi[8];
    {
        float th = -2.0f * (float)M_PI * (float)rl * (1.0f / 512.0f);
        float c1 = cosf(th), s1 = sinf(th);
        br[0] = 1.0f; bi[0] = 0.0f; br[1] = c1; bi[1] = s1;
#pragma unroll
        for (int r = 2; r < 8; r++) {
            float pr_ = br[r - 1], pi_ = bi[r - 1];
            br[r] = pr_ * c1 - pi_ * s1;
            bi[r] = pr_ * s1 + pi_ * c1;
        }
    }
    const int Lp = (int)(__brev((unsigned)((64 - rl) & 63)) >> 26);  // conj partner lane

    __syncthreads();
    const int lo = lo_lds[l];

    const int gw = blockIdx.x * WAVES + w;
    const int totw = NBLOCKS * WAVES;            // 6252
    const int npairs = (num_frames + 1) >> 1;    // 25000
    const int ngrp = (npairs + 1) >> 1;          // 12500 adjacent-pair groups

    for (int s = gw; s < ngrp; s += totw) {
        const long f0 = 4L * s;                  // 4 adjacent frames per group
        const bool hb0 = (f0 + 1) < num_frames;
        const bool vp1 = (2 * s + 1) < npairs;   // pair B exists
        const bool hb1 = (f0 + 3) < num_frames;

        // ---- 4 frame loads issued up front (independent, ~20 loads in flight) ----
        float vrA[8], viA[8], vrB[8], viB[8];
        load_pre(x, f0 * FRAME_STEP, l, true, vrA);
        load_pre(x, (f0 + 1) * FRAME_STEP, l, hb0, viA);
        load_pre(x, (f0 + 2) * FRAME_STEP, l, vp1, vrB);
        load_pre(x, (f0 + 3) * FRAME_STEP, l, vp1 && hb1, viB);

        // ---- 6 cross-lane stages, both pairs interleaved ----
#pragma unroll
        for (int j = 0; j < 6; j++)
            fftstage_x2(vrA, viA, vrB, viB, 32 >> j, cA[j], sA[j], sg[j]);
        twiddle_radix8(vrA, viA, br, bi);
        twiddle_radix8(vrB, viB, br, bi);

        // ---- untangle + power spectra -> LDS ----
        untangle_power(vrA, viA, l, rl, Lp, pw0);
        untangle_power(vrB, viB, l, rl, Lp, pw1);

        asm volatile("s_waitcnt lgkmcnt(0)" ::: "memory");  // wave-local LDS fence

        // ---- sparse mel matmul: 4 frames per weight read ----
        float ac0 = 1e-30f, ac1 = 1e-30f, ac2 = 1e-30f, ac3 = 1e-30f;
#pragma unroll
        for (int i = 0; i < WMAX; i++) {
            float wv = wc_lds[l * WSTRIDE + i];
            float2 p0 = *reinterpret_cast<const float2*>(&pw0[2 * (lo + i)]);
            float2 p1 = *reinterpret_cast<const float2*>(&pw1[2 * (lo + i)]);
            ac0 = fmaf(wv, p0.x, ac0);
            ac1 = fmaf(wv, p0.y, ac1);
            ac2 = fmaf(wv, p1.x, ac2);
            ac3 = fmaf(wv, p1.y, ac3);
        }

        // ---- per-frame normalize: 4 interleaved reduction chains ----
        float s0 = ac0, s1 = ac1, s2 = ac2, s3 = ac3;
        sum64x4(s0, s1, s2, s3);
        const float m0 = s0 * (1.0f/64.0f), m1 = s1 * (1.0f/64.0f);
        const float m2 = s2 * (1.0f/64.0f), m3 = s3 * (1.0f/64.0f);
        const float d0 = ac0 - m0, d1 = ac1 - m1, d2 = ac2 - m2, d3 = ac3 - m3;
        float q0 = d0*d0, q1 = d1*d1, q2 = d2*d2, q3 = d3*d3;
        sum64x4(q0, q1, q2, q3);

        out[f0 * NFILT + l] = d0 * rsqrtf(q0 * (1.0f/64.0f));
        if (hb0) out[(f0 + 1) * NFILT + l] = d1 * rsqrtf(q1 * (1.0f/64.0f));
        if (vp1) {
            out[(f0 + 2) * NFILT + l] = d2 * rsqrtf(q2 * (1.0f/64.0f));
            if (hb1) out[(f0 + 3) * NFILT + l] = d3 * rsqrtf(q3 * (1.0f/64.0f));
        }
    }
}

extern "C" void kernel_launch(void* const* d_in, const int* in_sizes, int n_in,
                              void* d_out, int out_size, void* d_ws, size_t ws_size,
                              hipStream_t stream) {
    (void)d_ws; (void)ws_size; (void)n_in; (void)in_sizes;
    const float* x = (const float*)d_in[0];
    const float* filters = (const float*)d_in[1];
    float* out = (float*)d_out;
    const int num_frames = out_size / NFILT;
    fbank_kernel<<<NBLOCKS, 256, 0, stream>>>(x, filters, out, num_frames);
}